// Round 1
// 188.447 us; speedup vs baseline: 1.0017x; 1.0017x over previous
//
#include <hip/hip_runtime.h>
#include <math.h>

#define N_ROWS  32768
#define K_CODES 1024
#define D_DIM   64
#define NSPLIT  4            // K-splits across blocks
#define C_SHIFT 30.0f        // logit shift keeps expf in fp32 range

// ---- ws float-index layout ----
#define WS_HIST   0                       // [1024] histogram (memset)
#define WS_ACC_H  1024                    // entropy sum (nats)
#define WS_ACC_C  1025                    // commitment sq-diff sum
#define WS_NUSED  1026                    // used-code count
#define WS_G      2048                    // [4096] 64x64 gram partial-summed (memset)
#define WS_E2C    6144                    // [1024] ||e||^2 + C_SHIFT
#define WS_PART   8192                    // 4 arrays of [NSPLIT*N_ROWS]
#define PART_STRIDE (NSPLIT * N_ROWS)     // 131072
#define WS_PART_S (WS_PART)
#define WS_PART_U (WS_PART + PART_STRIDE)
#define WS_PART_G (WS_PART + 2 * PART_STRIDE)
#define WS_PART_K (WS_PART + 3 * PART_STRIDE)
#define MEMSET_BYTES (6144 * 4)           // hist + accs + gram

// ---- out float-index layout (reference return order, concatenated) ----
#define OUT_Q      0
#define OUT_COMMIT 2097152
#define OUT_ORTHO  2097153
#define OUT_ENT    2097154
#define OUT_PERP   2097155
#define OUT_COV    2097156
#define OUT_IDX    2097157

__global__ __launch_bounds__(256) void vq_prep(const float* __restrict__ emb,
                                               const float* __restrict__ cc,
                                               float* __restrict__ ws) {
    int k = blockIdx.x * blockDim.x + threadIdx.x;
    if (k < K_CODES) {
        const float4* e4 = (const float4*)(emb + (size_t)k * D_DIM);
        float s = 0.f;
#pragma unroll
        for (int j = 0; j < 16; ++j) {
            float4 v = e4[j];
            s += v.x * v.x + v.y * v.y + v.z * v.z + v.w * v.w;
        }
        ws[WS_E2C + k] = s + C_SHIFT;
        if (cc[k] >= 1.0f) atomicAdd(&ws[WS_NUSED], 1.0f);
    }
}

// 2048 blocks x 256 threads. Block = (row-group, k-split): 64 rows (lane=row),
// 256 codes (64 per wave). Writes per-(row,split) softmax/argmax partials.
// __launch_bounds__(256, 4): min 4 waves/EU -> 128-VGPR budget so X[16]
// (64 VGPRs) stays in architectural registers. At the default 8-waves/EU
// target (64-VGPR budget) the compiler evicted X (VGPR_Count=44 measured),
// costing ~2.5x in shuffle/reload stalls (VALUBusy 43%).
__global__ __launch_bounds__(256, 4) void vq_main(const float* __restrict__ inp,
                                                  const float* __restrict__ emb,
                                                  float* __restrict__ ws) {
    __shared__ float Ls[4][64];
    __shared__ float Lu[4][64];
    __shared__ float Lg[4][64];
    __shared__ int   Lk[4][64];

    const int lane = threadIdx.x & 63;
    const int wave = threadIdx.x >> 6;
    const int rg   = blockIdx.x >> 2;      // row group 0..511
    const int sp   = blockIdx.x & 3;       // k split  0..3
    const int row  = rg * 64 + lane;

    float4 X[16];
    const float4* xr = (const float4*)(inp + (size_t)row * D_DIM);
#pragma unroll
    for (int j = 0; j < 16; ++j) X[j] = xr[j];

    // wave-uniform code base -> SGPR so embedding loads stay scalar
    const int kbase = __builtin_amdgcn_readfirstlane(sp * 256 + wave * 64);

    float s = 0.f, u = 0.f, gmax = -1e30f;
    int kb = kbase;

#pragma unroll 1
    for (int kk = 0; kk < 64; ++kk) {
        const int k = kbase + kk;
        const float4* e4 = (const float4*)(emb + (size_t)k * D_DIM);
        float d0 = 0.f, d1 = 0.f, d2 = 0.f, d3 = 0.f;
#pragma unroll
        for (int j = 0; j < 16; j += 4) {
            float4 ea = e4[j], eb = e4[j + 1], ec = e4[j + 2], ed = e4[j + 3];
            float4 xa = X[j], xb = X[j + 1], xc = X[j + 2], xd = X[j + 3];
            d0 = fmaf(ea.x, xa.x, d0); d0 = fmaf(ea.y, xa.y, d0);
            d0 = fmaf(ea.z, xa.z, d0); d0 = fmaf(ea.w, xa.w, d0);
            d1 = fmaf(eb.x, xb.x, d1); d1 = fmaf(eb.y, xb.y, d1);
            d1 = fmaf(eb.z, xb.z, d1); d1 = fmaf(eb.w, xb.w, d1);
            d2 = fmaf(ec.x, xc.x, d2); d2 = fmaf(ec.y, xc.y, d2);
            d2 = fmaf(ec.z, xc.z, d2); d2 = fmaf(ec.w, xc.w, d2);
            d3 = fmaf(ed.x, xd.x, d3); d3 = fmaf(ed.y, xd.y, d3);
            d3 = fmaf(ed.z, xd.z, d3); d3 = fmaf(ed.w, xd.w, d3);
        }
        float dot = (d0 + d1) + (d2 + d3);
        float g = fmaf(2.0f, dot, -ws[WS_E2C + k]);   // shifted logit
        float p = __expf(g);
        s += p;
        u = fmaf(p, g, u);
        if (g > gmax) { gmax = g; kb = k; }           // strict > = first-index ties
    }

    Ls[wave][lane] = s;
    Lu[wave][lane] = u;
    Lg[wave][lane] = gmax;
    Lk[wave][lane] = kb;
    __syncthreads();

    if (wave == 0) {
        float S = 0.f, U = 0.f, G = -1e30f;
        int I = 0;
#pragma unroll
        for (int w = 0; w < 4; ++w) {                 // ascending k order
            S += Ls[w][lane];
            U += Lu[w][lane];
            float gw = Lg[w][lane];
            if (gw > G) { G = gw; I = Lk[w][lane]; }
        }
        const int pi = sp * N_ROWS + row;
        ws[WS_PART_S + pi] = S;
        ws[WS_PART_U + pi] = U;
        ws[WS_PART_G + pi] = G;
        ws[WS_PART_K + pi] = (float)I;
    }
}

// 128 blocks x 256 threads; thread = row. Merge NSPLIT partials, epilogue.
__global__ __launch_bounds__(256) void vq_combine(const float* __restrict__ inp,
                                                  const float* __restrict__ emb,
                                                  float* __restrict__ ws,
                                                  float* __restrict__ out) {
    __shared__ float redH[4], redC[4];
    const int t   = threadIdx.x;
    const int row = blockIdx.x * 256 + t;

    float S = 0.f, U = 0.f, G = -1e30f;
    int I = 0;
#pragma unroll
    for (int sp = 0; sp < NSPLIT; ++sp) {             // ascending split order
        const int pi = sp * N_ROWS + row;
        S += ws[WS_PART_S + pi];
        U += ws[WS_PART_U + pi];
        float g = ws[WS_PART_G + pi];
        if (g > G) { G = g; I = (int)ws[WS_PART_K + pi]; }
    }
    float H = logf(S) - U / S;                        // per-row entropy (nats)

    out[OUT_IDX + row] = (float)I;
    atomicAdd(&ws[WS_HIST + I], 1.0f);

    const float4* xr = (const float4*)(inp + (size_t)row * D_DIM);
    const float4* q4 = (const float4*)(emb + (size_t)I * D_DIM);
    float4* oq = (float4*)out + (size_t)row * 16;
    float cs = 0.f;
#pragma unroll
    for (int j = 0; j < 16; ++j) {
        float4 q = q4[j], x = xr[j];
        float dx = q.x - x.x, dy = q.y - x.y, dz = q.z - x.z, dw = q.w - x.w;
        cs += dx * dx + dy * dy + dz * dz + dw * dw;
        float4 o;
        o.x = x.x + dx; o.y = x.y + dy; o.z = x.z + dz; o.w = x.w + dw;
        oq[j] = o;
    }
#pragma unroll
    for (int off = 32; off; off >>= 1) {
        H  += __shfl_down(H, off);
        cs += __shfl_down(cs, off);
    }
    if ((t & 63) == 0) { redH[t >> 6] = H; redC[t >> 6] = cs; }
    __syncthreads();
    if (t == 0) {
        atomicAdd(&ws[WS_ACC_H], redH[0] + redH[1] + redH[2] + redH[3]);
        atomicAdd(&ws[WS_ACC_C], redC[0] + redC[1] + redC[2] + redC[3]);
    }
}

// 16 blocks x 256 threads; block b owns codes [64b, 64b+64). Partial 64x64
// Gram of masked-normalized rows, atomicAdd into ws[WS_G].
__global__ __launch_bounds__(256) void vq_ortho_part(const float* __restrict__ emb,
                                                     const float* __restrict__ cc,
                                                     float* __restrict__ ws) {
    __shared__ float srows[64][64];
    __shared__ float rn2[64];

    const int t  = threadIdx.x;
    const int k0 = blockIdx.x * 64;
    const int rb = t >> 4;            // 0..15
    const int c4 = (t & 15) << 2;     // float4 col

#pragma unroll
    for (int i = 0; i < 4; ++i) {
        const int r = i * 16 + rb;
        float4 v = *(const float4*)(emb + (size_t)(k0 + r) * D_DIM + c4);
        *(float4*)(&srows[r][c4]) = v;
        float ss = v.x * v.x + v.y * v.y + v.z * v.z + v.w * v.w;
        ss += __shfl_down(ss, 8, 16);
        ss += __shfl_down(ss, 4, 16);
        ss += __shfl_down(ss, 2, 16);
        ss += __shfl_down(ss, 1, 16);
        if ((t & 15) == 0) {
            float nrm = fmaxf(sqrtf(ss), 1e-12f);
            float m = (cc[k0 + r] >= 1.0f) ? 1.0f : 0.0f;
            rn2[r] = m / (nrm * nrm);     // rnorm^2, folded into A side
        }
    }
    __syncthreads();

    const int a  = t >> 2;
    const int b0 = (t & 3) << 4;
    float acc[16];
#pragma unroll
    for (int i = 0; i < 16; ++i) acc[i] = 0.f;

#pragma unroll 4
    for (int k = 0; k < 64; ++k) {
        float na = srows[k][a] * rn2[k];
        const float* rbp = &srows[k][b0];
#pragma unroll
        for (int i = 0; i < 16; ++i) acc[i] = fmaf(na, rbp[i], acc[i]);
    }
#pragma unroll
    for (int i = 0; i < 16; ++i)
        atomicAdd(&ws[WS_G + a * 64 + b0 + i], acc[i]);
}

__global__ __launch_bounds__(256) void vq_finalize(const float* __restrict__ ws,
                                                   float* __restrict__ out) {
    __shared__ float redP[4], redG[4];
    const int t = threadIdx.x;
    float hp = 0.f, gg = 0.f;
    for (int k = t; k < K_CODES; k += 256) {
        float p = ws[WS_HIST + k] * (1.0f / (float)N_ROWS);
        hp += p * logf(p + 1e-10f);
    }
    for (int i = t; i < 4096; i += 256) {
        float g = ws[WS_G + i];
        gg = fmaf(g, g, gg);
    }
#pragma unroll
    for (int off = 32; off; off >>= 1) {
        hp += __shfl_down(hp, off);
        gg += __shfl_down(gg, off);
    }
    if ((t & 63) == 0) { redP[t >> 6] = hp; redG[t >> 6] = gg; }
    __syncthreads();
    if (t == 0) {
        float hsum = redP[0] + redP[1] + redP[2] + redP[3];
        float gsum = redG[0] + redG[1] + redG[2] + redG[3];
        float nu = ws[WS_NUSED];
        out[OUT_PERP]   = expf(-hsum);
        out[OUT_ENT]    = ws[WS_ACC_H] * (1.0f / (float)N_ROWS) * 0.1f; // /log2(1024)
        out[OUT_COMMIT] = ws[WS_ACC_C] * (1.0f / ((float)N_ROWS * (float)D_DIM));
        out[OUT_ORTHO]  = gsum / (nu * nu) - 1.0f / nu;
        out[OUT_COV]    = nu * (1.0f / (float)K_CODES);
    }
}

extern "C" void kernel_launch(void* const* d_in, const int* in_sizes, int n_in,
                              void* d_out, int out_size, void* d_ws, size_t ws_size,
                              hipStream_t stream) {
    const float* inp = (const float*)d_in[0];   // [16,2048,64]
    const float* emb = (const float*)d_in[1];   // [1024,64]
    const float* cc  = (const float*)d_in[2];   // [1024]
    float* out = (float*)d_out;
    float* ws  = (float*)d_ws;

    hipMemsetAsync(d_ws, 0, MEMSET_BYTES, stream);
    vq_prep<<<4, 256, 0, stream>>>(emb, cc, ws);
    vq_main<<<(N_ROWS / 64) * NSPLIT, 256, 0, stream>>>(inp, emb, ws);
    vq_combine<<<N_ROWS / 256, 256, 0, stream>>>(inp, emb, ws, out);
    vq_ortho_part<<<16, 256, 0, stream>>>(emb, cc, ws);
    vq_finalize<<<1, 256, 0, stream>>>(ws, out);
}

// Round 2
// 153.907 us; speedup vs baseline: 1.2265x; 1.2244x over previous
//
#include <hip/hip_runtime.h>
#include <math.h>

#define N_ROWS  32768
#define K_CODES 1024
#define D_DIM   64
#define C_SHIFT 30.0f        // logit shift keeps expf in fp32 range

// ---- ws float-index layout ----
#define WS_HIST   0                       // [1024] histogram (memset)
#define WS_ACC_H  1024                    // entropy sum (nats)
#define WS_ACC_C  1025                    // commitment sq-diff sum
#define WS_NUSED  1026                    // used-code count
#define WS_G      2048                    // [4096] 64x64 gram partials (memset)
#define WS_E2C    6144                    // [1024] ||e||^2 + C_SHIFT
// per-row partials, 2 K-splits each: [2*N_ROWS] per array
#define WS_PART_S 8192
#define WS_PART_U 73728
#define WS_PART_A 139264                  // approx-best code index (as float)
#define WS_PART_B 204800                  // approx-2nd  code index (as float)
// decomposed-E fragment records: 64 chunks x (6 frags x 64 lanes x 16B + 16 f32 e2)
#define WS_EB     270336
#define CHUNK_F4  388                     // float4s per chunk record (384 frag + 4 e2)
#define MAIN_CHUNKS 32                    // 16-code chunks per K-split
#define MEMSET_BYTES (6144 * 4)           // hist + accs + gram

// ---- out float-index layout (reference return order, concatenated) ----
#define OUT_Q      0
#define OUT_COMMIT 2097152
#define OUT_ORTHO  2097153
#define OUT_ENT    2097154
#define OUT_PERP   2097155
#define OUT_COV    2097156
#define OUT_IDX    2097157

typedef __attribute__((ext_vector_type(8))) short bf16x8;   // 8 bf16 = 4 VGPR
typedef __attribute__((ext_vector_type(4))) float f32x4;

// RNE fp32->bf16 (finite inputs), and exact bf16->fp32
__device__ inline unsigned short f2bf(float v) {
    unsigned int b = __float_as_uint(v);
    b += 0x7fffu + ((b >> 16) & 1u);
    return (unsigned short)(b >> 16);
}
__device__ inline float bf2f(unsigned short h) {
    return __uint_as_float(((unsigned int)h) << 16);
}
// v = hi + mid + lo (each bf16); residual subtractions are exact (Sterbenz)
__device__ inline void decomp3(float v, unsigned short &h, unsigned short &m,
                               unsigned short &l) {
    h = f2bf(v); float r1 = v - bf2f(h);
    m = f2bf(r1); float r2 = r1 - bf2f(m);
    l = f2bf(r2);
}
__device__ inline bf16x8 pack8(const unsigned short* u) {
    union { uint4 q; bf16x8 v; } cv;
    cv.q.x = (unsigned)u[0] | ((unsigned)u[1] << 16);
    cv.q.y = (unsigned)u[2] | ((unsigned)u[3] << 16);
    cv.q.z = (unsigned)u[4] | ((unsigned)u[5] << 16);
    cv.q.w = (unsigned)u[6] | ((unsigned)u[7] << 16);
    return cv.v;
}

// Bit-identical replica of the legacy fp32 logit chain (for candidate rescue)
__device__ inline float exact_g(const float4* X, const float* __restrict__ emb,
                                int k, float e2ck) {
    const float4* e4 = (const float4*)(emb + (size_t)k * D_DIM);
    float d0 = 0.f, d1 = 0.f, d2 = 0.f, d3 = 0.f;
#pragma unroll
    for (int j = 0; j < 16; j += 4) {
        float4 ea = e4[j], eb = e4[j + 1], ec = e4[j + 2], ed = e4[j + 3];
        float4 xa = X[j], xb = X[j + 1], xc = X[j + 2], xd = X[j + 3];
        d0 = fmaf(ea.x, xa.x, d0); d0 = fmaf(ea.y, xa.y, d0);
        d0 = fmaf(ea.z, xa.z, d0); d0 = fmaf(ea.w, xa.w, d0);
        d1 = fmaf(eb.x, xb.x, d1); d1 = fmaf(eb.y, xb.y, d1);
        d1 = fmaf(eb.z, xb.z, d1); d1 = fmaf(eb.w, xb.w, d1);
        d2 = fmaf(ec.x, xc.x, d2); d2 = fmaf(ec.y, xc.y, d2);
        d2 = fmaf(ec.z, xc.z, d2); d2 = fmaf(ec.w, xc.w, d2);
        d3 = fmaf(ed.x, xd.x, d3); d3 = fmaf(ed.y, xd.y, d3);
        d3 = fmaf(ed.z, xd.z, d3); d3 = fmaf(ed.w, xd.w, d3);
    }
    return fmaf(2.0f, (d0 + d1) + (d2 + d3), -e2ck);
}

__global__ __launch_bounds__(256) void vq_prep(const float* __restrict__ emb,
                                               const float* __restrict__ cc,
                                               float* __restrict__ ws) {
    int k = blockIdx.x * blockDim.x + threadIdx.x;
    if (k < K_CODES) {
        const float4* e4 = (const float4*)(emb + (size_t)k * D_DIM);
        float s = 0.f;
#pragma unroll
        for (int j = 0; j < 16; ++j) {
            float4 v = e4[j];
            s += v.x * v.x + v.y * v.y + v.z * v.z + v.w * v.w;
        }
        ws[WS_E2C + k] = s + C_SHIFT;
        // copy into the chunk record (read from LDS by vq_main)
        ws[WS_EB + (size_t)(k >> 4) * (CHUNK_F4 * 4) + 1536 + (k & 15)] = s + C_SHIFT;
        if (cc[k] >= 1.0f) atomicAdd(&ws[WS_NUSED], 1.0f);
    }
}

// Decompose E into MFMA-lane-layout bf16x3 fragments.
// Chunk c = codes [16c,16c+16); lane: col=lane&15 (code), k-elems=(lane>>4)*8+i.
__global__ __launch_bounds__(256) void vq_edec(const float* __restrict__ emb,
                                               float* __restrict__ ws) {
    const int tid  = blockIdx.x * 256 + threadIdx.x;   // 0..4095
    const int c    = tid >> 6;
    const int lane = tid & 63;
    const int code = c * 16 + (lane & 15);
    const int ko   = (lane >> 4) * 8;
    float4* EB4 = (float4*)(ws + WS_EB);
#pragma unroll
    for (int s = 0; s < 2; ++s) {
        const float* ep = emb + (size_t)code * D_DIM + s * 32 + ko;
        float4 A4 = *(const float4*)ep;
        float4 B4 = *(const float4*)(ep + 4);
        float v[8] = {A4.x, A4.y, A4.z, A4.w, B4.x, B4.y, B4.z, B4.w};
        unsigned short H[8], M[8], L[8];
#pragma unroll
        for (int i = 0; i < 8; ++i) decomp3(v[i], H[i], M[i], L[i]);
        union { bf16x8 v8; float4 f; } th, tm, tl;
        th.v8 = pack8(H); tm.v8 = pack8(M); tl.v8 = pack8(L);
        const int base = c * CHUNK_F4 + s * 192;       // s*3*64
        EB4[base + 0 * 64 + lane] = th.f;
        EB4[base + 1 * 64 + lane] = tm.f;
        EB4[base + 2 * 64 + lane] = tl.f;
    }
}

// 1024 blocks x 256 thr. Block = (row-group of 64, K-split of 512 codes).
// Wave = 16 rows x 512 codes via 16x16x32 bf16 MFMA, bf16x3 (6-term) emulation.
// Per 16-code chunk: stage B-frags to LDS (dbuf), 12 MFMA, fused exp/top-2.
__global__ __launch_bounds__(256, 4) void vq_main(const float* __restrict__ inp,
                                                  float* __restrict__ ws) {
    __shared__ float4 sbuf[2][CHUNK_F4];
    const int t    = threadIdx.x;
    const int lane = t & 63;
    const int wave = t >> 6;
    const int col  = lane & 15;
    const int kg   = lane >> 4;
    const int rg   = blockIdx.x >> 1;
    const int sp   = blockIdx.x & 1;
    const int row  = rg * 64 + wave * 16 + col;

    // ---- decompose this lane's X-slice into 6 A-frags (2 k-steps x hi/mid/lo)
    bf16x8 xh0, xm0, xl0, xh1, xm1, xl1;
    {
        const float* xp = inp + (size_t)row * D_DIM + kg * 8;
        float4 A4 = *(const float4*)xp;
        float4 B4 = *(const float4*)(xp + 4);
        float v[8] = {A4.x, A4.y, A4.z, A4.w, B4.x, B4.y, B4.z, B4.w};
        unsigned short H[8], M[8], L[8];
#pragma unroll
        for (int i = 0; i < 8; ++i) decomp3(v[i], H[i], M[i], L[i]);
        xh0 = pack8(H); xm0 = pack8(M); xl0 = pack8(L);
        A4 = *(const float4*)(xp + 32);
        B4 = *(const float4*)(xp + 36);
        float w[8] = {A4.x, A4.y, A4.z, A4.w, B4.x, B4.y, B4.z, B4.w};
#pragma unroll
        for (int i = 0; i < 8; ++i) decomp3(w[i], H[i], M[i], L[i]);
        xh1 = pack8(H); xm1 = pack8(M); xl1 = pack8(L);
    }

    const float4* EB4 = (const float4*)(ws + WS_EB)
                      + (size_t)sp * MAIN_CHUNKS * CHUNK_F4;

    // stage chunk 0
    sbuf[0][t] = EB4[t];
    if (t < CHUNK_F4 - 256) sbuf[0][256 + t] = EB4[256 + t];
    __syncthreads();

    float sa[4], ua[4], m1[4], m2[4];
    int i1[4], i2[4];
#pragma unroll
    for (int q = 0; q < 4; ++q) {
        sa[q] = 0.f; ua[q] = 0.f;
        m1[q] = -1e30f; m2[q] = -1e30f; i1[q] = 0; i2[q] = 0;
    }

    int cur = 0;
    for (int c = 0; c < MAIN_CHUNKS; ++c) {
        // T14 split: issue next chunk's global loads early, ds_write late
        const int cn = (c < MAIN_CHUNKS - 1) ? c + 1 : c;
        float4 p0 = EB4[(size_t)cn * CHUNK_F4 + t];
        float4 p1;
        if (t < CHUNK_F4 - 256) p1 = EB4[(size_t)cn * CHUNK_F4 + 256 + t];

        const bf16x8* B = (const bf16x8*)(&sbuf[cur][0]);
        bf16x8 b00 = B[0 * 64 + lane];
        bf16x8 b01 = B[1 * 64 + lane];
        bf16x8 b02 = B[2 * 64 + lane];
        bf16x8 b10 = B[3 * 64 + lane];
        bf16x8 b11 = B[4 * 64 + lane];
        bf16x8 b12 = B[5 * 64 + lane];
        const float e2v = ((const float*)(&sbuf[cur][384]))[col];

        f32x4 acc = {0.f, 0.f, 0.f, 0.f};
        // 6-term bf16x3: (h,h) (h,m) (m,h) (h,l) (l,h) (m,m), 2 k-steps
        acc = __builtin_amdgcn_mfma_f32_16x16x32_bf16(xh0, b00, acc, 0, 0, 0);
        acc = __builtin_amdgcn_mfma_f32_16x16x32_bf16(xh0, b01, acc, 0, 0, 0);
        acc = __builtin_amdgcn_mfma_f32_16x16x32_bf16(xm0, b00, acc, 0, 0, 0);
        acc = __builtin_amdgcn_mfma_f32_16x16x32_bf16(xh0, b02, acc, 0, 0, 0);
        acc = __builtin_amdgcn_mfma_f32_16x16x32_bf16(xl0, b00, acc, 0, 0, 0);
        acc = __builtin_amdgcn_mfma_f32_16x16x32_bf16(xm0, b01, acc, 0, 0, 0);
        acc = __builtin_amdgcn_mfma_f32_16x16x32_bf16(xh1, b10, acc, 0, 0, 0);
        acc = __builtin_amdgcn_mfma_f32_16x16x32_bf16(xh1, b11, acc, 0, 0, 0);
        acc = __builtin_amdgcn_mfma_f32_16x16x32_bf16(xm1, b10, acc, 0, 0, 0);
        acc = __builtin_amdgcn_mfma_f32_16x16x32_bf16(xh1, b12, acc, 0, 0, 0);
        acc = __builtin_amdgcn_mfma_f32_16x16x32_bf16(xl1, b10, acc, 0, 0, 0);
        acc = __builtin_amdgcn_mfma_f32_16x16x32_bf16(xm1, b11, acc, 0, 0, 0);

        const int cbase = (sp * MAIN_CHUNKS + c) * 16 + col;
#pragma unroll
        for (int q = 0; q < 4; ++q) {
            float g = fmaf(2.f, acc[q], -e2v);       // shifted logit (approx)
            float p = __expf(g);
            sa[q] += p;
            ua[q] = fmaf(p, g, ua[q]);
            bool gt1 = g > m1[q];
            bool gt2 = g > m2[q];
            m2[q] = gt1 ? m1[q] : (gt2 ? g : m2[q]);
            i2[q] = gt1 ? i1[q] : (gt2 ? cbase : i2[q]);
            m1[q] = gt1 ? g : m1[q];
            i1[q] = gt1 ? cbase : i1[q];
        }

        sbuf[cur ^ 1][t] = p0;
        if (t < CHUNK_F4 - 256) sbuf[cur ^ 1][256 + t] = p1;
        __syncthreads();
        cur ^= 1;
    }

    // per-row reduce across the 16 lanes sharing each C-row (xor over low 4 bits)
#pragma unroll
    for (int off = 1; off < 16; off <<= 1) {
#pragma unroll
        for (int q = 0; q < 4; ++q) {
            sa[q] += __shfl_xor(sa[q], off);
            ua[q] += __shfl_xor(ua[q], off);
            float bm1 = __shfl_xor(m1[q], off);
            int   bi1 = __shfl_xor(i1[q], off);
            float bm2 = __shfl_xor(m2[q], off);
            int   bi2 = __shfl_xor(i2[q], off);
            if (bm1 > m1[q]) {
                m2[q] = m1[q]; i2[q] = i1[q];
                m1[q] = bm1;   i1[q] = bi1;
                if (bm2 > m2[q]) { m2[q] = bm2; i2[q] = bi2; }
            } else if (bm1 > m2[q]) {
                m2[q] = bm1; i2[q] = bi1;
            }
        }
    }

    if (col == 0) {
        // C rows for this lane: (lane>>4)*4 + q
        const int r0 = rg * 64 + wave * 16 + kg * 4;
        const int pb = sp * N_ROWS;
#pragma unroll
        for (int q = 0; q < 4; ++q) {
            ws[WS_PART_S + pb + r0 + q] = sa[q];
            ws[WS_PART_U + pb + r0 + q] = ua[q];
            ws[WS_PART_A + pb + r0 + q] = (float)i1[q];
            ws[WS_PART_B + pb + r0 + q] = (float)i2[q];
        }
    }
}

// 128 blocks x 256 thr; thread = row. Merge 2 splits, exact fp32 rescue of the
// <=4 approx candidates (legacy FMA chain -> bitwise-legacy argmin), epilogue.
__global__ __launch_bounds__(256) void vq_combine(const float* __restrict__ inp,
                                                  const float* __restrict__ emb,
                                                  float* __restrict__ ws,
                                                  float* __restrict__ out) {
    __shared__ float redH[4], redC[4];
    const int t   = threadIdx.x;
    const int row = blockIdx.x * 256 + t;

    float S = ws[WS_PART_S + row] + ws[WS_PART_S + N_ROWS + row];
    float U = ws[WS_PART_U + row] + ws[WS_PART_U + N_ROWS + row];

    float4 X[16];
    const float4* xr = (const float4*)(inp + (size_t)row * D_DIM);
#pragma unroll
    for (int j = 0; j < 16; ++j) X[j] = xr[j];

    const int c0 = (int)ws[WS_PART_A + row];
    const int c1 = (int)ws[WS_PART_B + row];
    const int c2 = (int)ws[WS_PART_A + N_ROWS + row];
    const int c3 = (int)ws[WS_PART_B + N_ROWS + row];

    float bestg = -1e30f; int I = K_CODES;
    {
        float g0 = exact_g(X, emb, c0, ws[WS_E2C + c0]);
        float g1 = exact_g(X, emb, c1, ws[WS_E2C + c1]);
        float g2 = exact_g(X, emb, c2, ws[WS_E2C + c2]);
        float g3 = exact_g(X, emb, c3, ws[WS_E2C + c3]);
        // argmax with ties -> lowest index == legacy ascending-k strict-> scan
        if (g0 > bestg || (g0 == bestg && c0 < I)) { bestg = g0; I = c0; }
        if (g1 > bestg || (g1 == bestg && c1 < I)) { bestg = g1; I = c1; }
        if (g2 > bestg || (g2 == bestg && c2 < I)) { bestg = g2; I = c2; }
        if (g3 > bestg || (g3 == bestg && c3 < I)) { bestg = g3; I = c3; }
    }

    float H = logf(S) - U / S;                        // per-row entropy (nats)

    out[OUT_IDX + row] = (float)I;
    atomicAdd(&ws[WS_HIST + I], 1.0f);

    const float4* q4 = (const float4*)(emb + (size_t)I * D_DIM);
    float4* oq = (float4*)out + (size_t)row * 16;
    float cs = 0.f;
#pragma unroll
    for (int j = 0; j < 16; ++j) {
        float4 q = q4[j], x = X[j];
        float dx = q.x - x.x, dy = q.y - x.y, dz = q.z - x.z, dw = q.w - x.w;
        cs += dx * dx + dy * dy + dz * dz + dw * dw;
        float4 o;
        o.x = x.x + dx; o.y = x.y + dy; o.z = x.z + dz; o.w = x.w + dw;
        oq[j] = o;
    }
#pragma unroll
    for (int off = 32; off; off >>= 1) {
        H  += __shfl_down(H, off);
        cs += __shfl_down(cs, off);
    }
    if ((t & 63) == 0) { redH[t >> 6] = H; redC[t >> 6] = cs; }
    __syncthreads();
    if (t == 0) {
        atomicAdd(&ws[WS_ACC_H], redH[0] + redH[1] + redH[2] + redH[3]);
        atomicAdd(&ws[WS_ACC_C], redC[0] + redC[1] + redC[2] + redC[3]);
    }
}

// 16 blocks x 256 threads; block b owns codes [64b, 64b+64). Partial 64x64
// Gram of masked-normalized rows, atomicAdd into ws[WS_G].
__global__ __launch_bounds__(256) void vq_ortho_part(const float* __restrict__ emb,
                                                     const float* __restrict__ cc,
                                                     float* __restrict__ ws) {
    __shared__ float srows[64][64];
    __shared__ float rn2[64];

    const int t  = threadIdx.x;
    const int k0 = blockIdx.x * 64;
    const int rb = t >> 4;            // 0..15
    const int c4 = (t & 15) << 2;     // float4 col

#pragma unroll
    for (int i = 0; i < 4; ++i) {
        const int r = i * 16 + rb;
        float4 v = *(const float4*)(emb + (size_t)(k0 + r) * D_DIM + c4);
        *(float4*)(&srows[r][c4]) = v;
        float ss = v.x * v.x + v.y * v.y + v.z * v.z + v.w * v.w;
        ss += __shfl_down(ss, 8, 16);
        ss += __shfl_down(ss, 4, 16);
        ss += __shfl_down(ss, 2, 16);
        ss += __shfl_down(ss, 1, 16);
        if ((t & 15) == 0) {
            float nrm = fmaxf(sqrtf(ss), 1e-12f);
            float m = (cc[k0 + r] >= 1.0f) ? 1.0f : 0.0f;
            rn2[r] = m / (nrm * nrm);     // rnorm^2, folded into A side
        }
    }
    __syncthreads();

    const int a  = t >> 2;
    const int b0 = (t & 3) << 4;
    float acc[16];
#pragma unroll
    for (int i = 0; i < 16; ++i) acc[i] = 0.f;

#pragma unroll 4
    for (int k = 0; k < 64; ++k) {
        float na = srows[k][a] * rn2[k];
        const float* rbp = &srows[k][b0];
#pragma unroll
        for (int i = 0; i < 16; ++i) acc[i] = fmaf(na, rbp[i], acc[i]);
    }
#pragma unroll
    for (int i = 0; i < 16; ++i)
        atomicAdd(&ws[WS_G + a * 64 + b0 + i], acc[i]);
}

__global__ __launch_bounds__(256) void vq_finalize(const float* __restrict__ ws,
                                                   float* __restrict__ out) {
    __shared__ float redP[4], redG[4];
    const int t = threadIdx.x;
    float hp = 0.f, gg = 0.f;
    for (int k = t; k < K_CODES; k += 256) {
        float p = ws[WS_HIST + k] * (1.0f / (float)N_ROWS);
        hp += p * logf(p + 1e-10f);
    }
    for (int i = t; i < 4096; i += 256) {
        float g = ws[WS_G + i];
        gg = fmaf(g, g, gg);
    }
#pragma unroll
    for (int off = 32; off; off >>= 1) {
        hp += __shfl_down(hp, off);
        gg += __shfl_down(gg, off);
    }
    if ((t & 63) == 0) { redP[t >> 6] = hp; redG[t >> 6] = gg; }
    __syncthreads();
    if (t == 0) {
        float hsum = redP[0] + redP[1] + redP[2] + redP[3];
        float gsum = redG[0] + redG[1] + redG[2] + redG[3];
        float nu = ws[WS_NUSED];
        out[OUT_PERP]   = expf(-hsum);
        out[OUT_ENT]    = ws[WS_ACC_H] * (1.0f / (float)N_ROWS) * 0.1f; // /log2(1024)
        out[OUT_COMMIT] = ws[WS_ACC_C] * (1.0f / ((float)N_ROWS * (float)D_DIM));
        out[OUT_ORTHO]  = gsum / (nu * nu) - 1.0f / nu;
        out[OUT_COV]    = nu * (1.0f / (float)K_CODES);
    }
}

extern "C" void kernel_launch(void* const* d_in, const int* in_sizes, int n_in,
                              void* d_out, int out_size, void* d_ws, size_t ws_size,
                              hipStream_t stream) {
    const float* inp = (const float*)d_in[0];   // [16,2048,64]
    const float* emb = (const float*)d_in[1];   // [1024,64]
    const float* cc  = (const float*)d_in[2];   // [1024]
    float* out = (float*)d_out;
    float* ws  = (float*)d_ws;

    hipMemsetAsync(d_ws, 0, MEMSET_BYTES, stream);
    vq_prep<<<4, 256, 0, stream>>>(emb, cc, ws);
    vq_edec<<<16, 256, 0, stream>>>(emb, ws);
    vq_main<<<(N_ROWS / 64) * 2, 256, 0, stream>>>(inp, ws);
    vq_combine<<<N_ROWS / 256, 256, 0, stream>>>(inp, emb, ws, out);
    vq_ortho_part<<<16, 256, 0, stream>>>(emb, cc, ws);
    vq_finalize<<<1, 256, 0, stream>>>(ws, out);
}

// Round 3
// 150.071 us; speedup vs baseline: 1.2579x; 1.0256x over previous
//
#include <hip/hip_runtime.h>
#include <math.h>

#define N_ROWS  32768
#define K_CODES 1024
#define D_DIM   64
#define C_SHIFT 30.0f        // logit shift keeps expf in fp32 range
#define LOG2E_F 1.4426950408889634f
#define LN2_F   0.6931471805599453f

// ---- ws float-index layout ----
#define WS_HIST   0                       // [1024] histogram (memset)
#define WS_ACC_H  1024                    // entropy sum (base-2 weighted)
#define WS_ACC_C  1025                    // commitment sq-diff sum
#define WS_NUSED  1026                    // used-code count
#define WS_G      2048                    // [4096] 64x64 gram partials (memset)
#define WS_E2C    6144                    // [1024] ||e||^2 + C_SHIFT (legacy order)
// per-row partials, 2 K-splits each: [2*N_ROWS] per array
#define WS_PART_S 8192
#define WS_PART_U 73728
#define WS_PART_A 139264                  // approx-best code index (as float)
#define WS_PART_B 204800                  // approx-2nd  code index (as float)
// decomposed-E fragment records: 64 chunks x (6 frags x 64 lanes x 16B + 16 f32 e2l)
#define WS_EB     270336
#define CHUNK_F4  388                     // float4s per chunk record (384 frag + 4 e2)
#define MAIN_CHUNKS 32                    // 16-code chunks per K-split
#define MEMSET_BYTES (6144 * 4)           // hist + accs + gram

// ---- out float-index layout (reference return order, concatenated) ----
#define OUT_Q      0
#define OUT_COMMIT 2097152
#define OUT_ORTHO  2097153
#define OUT_ENT    2097154
#define OUT_PERP   2097155
#define OUT_COV    2097156
#define OUT_IDX    2097157

typedef __attribute__((ext_vector_type(8))) short bf16x8;   // 8 bf16 = 4 VGPR
typedef __attribute__((ext_vector_type(4))) float f32x4;

// RNE fp32->bf16 (finite inputs), and exact bf16->fp32
__device__ inline unsigned short f2bf(float v) {
    unsigned int b = __float_as_uint(v);
    b += 0x7fffu + ((b >> 16) & 1u);
    return (unsigned short)(b >> 16);
}
__device__ inline float bf2f(unsigned short h) {
    return __uint_as_float(((unsigned int)h) << 16);
}
// v = hi + mid + lo (each bf16); residual subtractions are exact
__device__ inline void decomp3(float v, unsigned short &h, unsigned short &m,
                               unsigned short &l) {
    h = f2bf(v); float r1 = v - bf2f(h);
    m = f2bf(r1); float r2 = r1 - bf2f(m);
    l = f2bf(r2);
}
__device__ inline bf16x8 pack8(const unsigned short* u) {
    union { uint4 q; bf16x8 v; } cv;
    cv.q.x = (unsigned)u[0] | ((unsigned)u[1] << 16);
    cv.q.y = (unsigned)u[2] | ((unsigned)u[3] << 16);
    cv.q.z = (unsigned)u[4] | ((unsigned)u[5] << 16);
    cv.q.w = (unsigned)u[6] | ((unsigned)u[7] << 16);
    return cv.v;
}

// Bit-identical replica of the legacy fp32 logit chain (for candidate rescue)
__device__ inline float exact_g(const float4* X, const float* __restrict__ emb,
                                int k, float e2ck) {
    const float4* e4 = (const float4*)(emb + (size_t)k * D_DIM);
    float d0 = 0.f, d1 = 0.f, d2 = 0.f, d3 = 0.f;
#pragma unroll
    for (int j = 0; j < 16; j += 4) {
        float4 ea = e4[j], eb = e4[j + 1], ec = e4[j + 2], ed = e4[j + 3];
        float4 xa = X[j], xb = X[j + 1], xc = X[j + 2], xd = X[j + 3];
        d0 = fmaf(ea.x, xa.x, d0); d0 = fmaf(ea.y, xa.y, d0);
        d0 = fmaf(ea.z, xa.z, d0); d0 = fmaf(ea.w, xa.w, d0);
        d1 = fmaf(eb.x, xb.x, d1); d1 = fmaf(eb.y, xb.y, d1);
        d1 = fmaf(eb.z, xb.z, d1); d1 = fmaf(eb.w, xb.w, d1);
        d2 = fmaf(ec.x, xc.x, d2); d2 = fmaf(ec.y, xc.y, d2);
        d2 = fmaf(ec.z, xc.z, d2); d2 = fmaf(ec.w, xc.w, d2);
        d3 = fmaf(ed.x, xd.x, d3); d3 = fmaf(ed.y, xd.y, d3);
        d3 = fmaf(ed.z, xd.z, d3); d3 = fmaf(ed.w, xd.w, d3);
    }
    return fmaf(2.0f, (d0 + d1) + (d2 + d3), -e2ck);
}

// Fused prep: E-fragment decomposition (MFMA lane layout) + ||e||^2 + nused.
// 16 blocks x 256; thread tid -> (chunk c = tid>>6, lane). col=lane&15 (code),
// kg=lane>>4 selects k-elems (kg*8 within each 32-wide k-step).
__global__ __launch_bounds__(256) void vq_prep(const float* __restrict__ emb,
                                               const float* __restrict__ cc,
                                               float* __restrict__ ws) {
    const int tid  = blockIdx.x * 256 + threadIdx.x;   // 0..4095
    const int c    = tid >> 6;
    const int lane = tid & 63;
    const int col  = lane & 15;
    const int kg   = lane >> 4;
    const int code = c * 16 + col;
    float4* EB4 = (float4*)(ws + WS_EB);
#pragma unroll
    for (int s = 0; s < 2; ++s) {
        const float* ep = emb + (size_t)code * D_DIM + s * 32 + kg * 8;
        float4 A4 = *(const float4*)ep;
        float4 B4 = *(const float4*)(ep + 4);
        float v[8] = {A4.x, A4.y, A4.z, A4.w, B4.x, B4.y, B4.z, B4.w};
        unsigned short H[8], M[8], L[8];
#pragma unroll
        for (int i = 0; i < 8; ++i) decomp3(v[i], H[i], M[i], L[i]);
        union { bf16x8 v8; float4 f; } th, tm, tl;
        th.v8 = pack8(H); tm.v8 = pack8(M); tl.v8 = pack8(L);
        const int base = c * CHUNK_F4 + s * 192;       // s*3*64
        EB4[base + 0 * 64 + lane] = th.f;
        EB4[base + 1 * 64 + lane] = tm.f;
        EB4[base + 2 * 64 + lane] = tl.f;
    }
    if (kg == 0) {
        // legacy sequential order -> ws[WS_E2C] bitwise matches rounds 0-2
        const float4* e4 = (const float4*)(emb + (size_t)code * D_DIM);
        float ssum = 0.f;
#pragma unroll
        for (int j = 0; j < 16; ++j) {
            float4 v = e4[j];
            ssum += v.x * v.x + v.y * v.y + v.z * v.z + v.w * v.w;
        }
        float e2c = ssum + C_SHIFT;
        ws[WS_E2C + code] = e2c;
        ((float*)(EB4 + c * CHUNK_F4 + 384))[col] = e2c * LOG2E_F;  // base-2 scaled
        if (cc[code] >= 1.0f) atomicAdd(&ws[WS_NUSED], 1.0f);
    }
}

#define MFMA_BF16 __builtin_amdgcn_mfma_f32_16x16x32_bf16

// 1024 blocks x 256 thr. Block = (row-group of 64, K-split of 512 codes).
// Wave = 16 rows x 512 codes via 16x16x32 bf16 MFMA, bf16x3 (6-term) emulation.
// NO LDS, NO BARRIERS: the 397 KB fragment table is L2/L3-resident (FETCH_SIZE
// showed ~inp only), so each wave streams B-frags global->reg with 1-chunk
// prefetch. Waves fully independent.
__global__ __launch_bounds__(256, 4) void vq_main(const float* __restrict__ inp,
                                                  float* __restrict__ ws) {
    const int t    = threadIdx.x;
    const int lane = t & 63;
    const int wave = t >> 6;
    const int col  = lane & 15;
    const int kg   = lane >> 4;
    const int rg   = blockIdx.x >> 1;
    const int sp   = blockIdx.x & 1;
    const int row  = rg * 64 + wave * 16 + col;

    // ---- decompose this lane's X-slice into 6 A-frags (2 k-steps x hi/mid/lo)
    bf16x8 xh0, xm0, xl0, xh1, xm1, xl1;
    {
        const float* xp = inp + (size_t)row * D_DIM + kg * 8;
        float4 A4 = *(const float4*)xp;
        float4 B4 = *(const float4*)(xp + 4);
        float v[8] = {A4.x, A4.y, A4.z, A4.w, B4.x, B4.y, B4.z, B4.w};
        unsigned short H[8], M[8], L[8];
#pragma unroll
        for (int i = 0; i < 8; ++i) decomp3(v[i], H[i], M[i], L[i]);
        xh0 = pack8(H); xm0 = pack8(M); xl0 = pack8(L);
        A4 = *(const float4*)(xp + 32);
        B4 = *(const float4*)(xp + 36);
        float w[8] = {A4.x, A4.y, A4.z, A4.w, B4.x, B4.y, B4.z, B4.w};
#pragma unroll
        for (int i = 0; i < 8; ++i) decomp3(w[i], H[i], M[i], L[i]);
        xh1 = pack8(H); xm1 = pack8(M); xl1 = pack8(L);
    }

    const float4* EBp = (const float4*)(ws + WS_EB)
                      + (size_t)sp * MAIN_CHUNKS * CHUNK_F4;

    float sa[4], ua[4], m1[4], m2[4];
    int i1[4], i2[4];
#pragma unroll
    for (int q = 0; q < 4; ++q) {
        sa[q] = 0.f; ua[q] = 0.f;
        m1[q] = -1e30f; m2[q] = -1e30f; i1[q] = 0; i2[q] = 0;
    }

    // prefetch chunk 0
    bf16x8 cb0, cb1, cb2, cb3, cb4, cb5; float ce2;
    {
        const float4* p = EBp;
        const bf16x8* pb = (const bf16x8*)p;
        cb0 = pb[0 * 64 + lane]; cb1 = pb[1 * 64 + lane]; cb2 = pb[2 * 64 + lane];
        cb3 = pb[3 * 64 + lane]; cb4 = pb[4 * 64 + lane]; cb5 = pb[5 * 64 + lane];
        ce2 = ((const float*)(p + 384))[col];
    }

#pragma unroll 2
    for (int c = 0; c < MAIN_CHUNKS; ++c) {
        // issue next chunk's loads before compute (latency hides under MFMA+VALU)
        bf16x8 nb0, nb1, nb2, nb3, nb4, nb5; float ne2;
        {
            const int cn = (c + 1 < MAIN_CHUNKS) ? c + 1 : c;
            const float4* p = EBp + (size_t)cn * CHUNK_F4;
            const bf16x8* pb = (const bf16x8*)p;
            nb0 = pb[0 * 64 + lane]; nb1 = pb[1 * 64 + lane]; nb2 = pb[2 * 64 + lane];
            nb3 = pb[3 * 64 + lane]; nb4 = pb[4 * 64 + lane]; nb5 = pb[5 * 64 + lane];
            ne2 = ((const float*)(p + 384))[col];
        }

        // two independent accumulator chains (k-step 0 / k-step 1)
        f32x4 a0 = {0.f, 0.f, 0.f, 0.f};
        f32x4 a1 = {0.f, 0.f, 0.f, 0.f};
        a0 = MFMA_BF16(xh0, cb0, a0, 0, 0, 0);
        a1 = MFMA_BF16(xh1, cb3, a1, 0, 0, 0);
        a0 = MFMA_BF16(xh0, cb1, a0, 0, 0, 0);
        a1 = MFMA_BF16(xh1, cb4, a1, 0, 0, 0);
        a0 = MFMA_BF16(xm0, cb0, a0, 0, 0, 0);
        a1 = MFMA_BF16(xm1, cb3, a1, 0, 0, 0);
        a0 = MFMA_BF16(xh0, cb2, a0, 0, 0, 0);
        a1 = MFMA_BF16(xh1, cb5, a1, 0, 0, 0);
        a0 = MFMA_BF16(xl0, cb0, a0, 0, 0, 0);
        a1 = MFMA_BF16(xl1, cb3, a1, 0, 0, 0);
        a0 = MFMA_BF16(xm0, cb1, a0, 0, 0, 0);
        a1 = MFMA_BF16(xm1, cb4, a1, 0, 0, 0);

        const int cbase = (sp * MAIN_CHUNKS + c) * 16 + col;
#pragma unroll
        for (int q = 0; q < 4; ++q) {
            // base-2 shifted logit: g2 = 2*log2e*dot - log2e*(e2+C_SHIFT)
            float g = fmaf(2.0f * LOG2E_F, a0[q] + a1[q], -ce2);
            float p;
            asm("v_exp_f32 %0, %1" : "=v"(p) : "v"(g));   // p = 2^g
            sa[q] += p;
            ua[q] = fmaf(p, g, ua[q]);                    // base-2 weighted
            bool gt1 = g > m1[q];
            bool gt2 = g > m2[q];
            m2[q] = gt1 ? m1[q] : (gt2 ? g : m2[q]);
            i2[q] = gt1 ? i1[q] : (gt2 ? cbase : i2[q]);
            m1[q] = gt1 ? g : m1[q];
            i1[q] = gt1 ? cbase : i1[q];
        }

        cb0 = nb0; cb1 = nb1; cb2 = nb2; cb3 = nb3; cb4 = nb4; cb5 = nb5;
        ce2 = ne2;
    }

    // per-row reduce across the 16 lanes sharing each C-row
#pragma unroll
    for (int off = 1; off < 16; off <<= 1) {
#pragma unroll
        for (int q = 0; q < 4; ++q) {
            sa[q] += __shfl_xor(sa[q], off);
            ua[q] += __shfl_xor(ua[q], off);
            float bm1 = __shfl_xor(m1[q], off);
            int   bi1 = __shfl_xor(i1[q], off);
            float bm2 = __shfl_xor(m2[q], off);
            int   bi2 = __shfl_xor(i2[q], off);
            if (bm1 > m1[q]) {
                m2[q] = m1[q]; i2[q] = i1[q];
                m1[q] = bm1;   i1[q] = bi1;
                if (bm2 > m2[q]) { m2[q] = bm2; i2[q] = bi2; }
            } else if (bm1 > m2[q]) {
                m2[q] = bm1; i2[q] = bi1;
            }
        }
    }

    if (col == 0) {
        const int r0 = rg * 64 + wave * 16 + kg * 4;   // C rows: kg*4 + q
        const int pb = sp * N_ROWS;
#pragma unroll
        for (int q = 0; q < 4; ++q) {
            ws[WS_PART_S + pb + r0 + q] = sa[q];
            ws[WS_PART_U + pb + r0 + q] = ua[q];
            ws[WS_PART_A + pb + r0 + q] = (float)i1[q];
            ws[WS_PART_B + pb + r0 + q] = (float)i2[q];
        }
    }
}

// 128 blocks x 256 thr; thread = row. Merge 2 splits, exact fp32 rescue of the
// <=4 approx candidates (legacy FMA chain -> legacy argmin semantics), epilogue.
__global__ __launch_bounds__(256) void vq_combine(const float* __restrict__ inp,
                                                  const float* __restrict__ emb,
                                                  float* __restrict__ ws,
                                                  float* __restrict__ out) {
    __shared__ float redH[4], redC[4];
    const int t   = threadIdx.x;
    const int row = blockIdx.x * 256 + t;

    float S = ws[WS_PART_S + row] + ws[WS_PART_S + N_ROWS + row];
    float U2 = ws[WS_PART_U + row] + ws[WS_PART_U + N_ROWS + row];
    float U = U2 * LN2_F;                             // base-2 -> nats

    float4 X[16];
    const float4* xr = (const float4*)(inp + (size_t)row * D_DIM);
#pragma unroll
    for (int j = 0; j < 16; ++j) X[j] = xr[j];

    const int c0 = (int)ws[WS_PART_A + row];
    const int c1 = (int)ws[WS_PART_B + row];
    const int c2 = (int)ws[WS_PART_A + N_ROWS + row];
    const int c3 = (int)ws[WS_PART_B + N_ROWS + row];

    float bestg = -1e30f; int I = K_CODES;
    {
        float g0 = exact_g(X, emb, c0, ws[WS_E2C + c0]);
        float g1 = exact_g(X, emb, c1, ws[WS_E2C + c1]);
        float g2 = exact_g(X, emb, c2, ws[WS_E2C + c2]);
        float g3 = exact_g(X, emb, c3, ws[WS_E2C + c3]);
        if (g0 > bestg || (g0 == bestg && c0 < I)) { bestg = g0; I = c0; }
        if (g1 > bestg || (g1 == bestg && c1 < I)) { bestg = g1; I = c1; }
        if (g2 > bestg || (g2 == bestg && c2 < I)) { bestg = g2; I = c2; }
        if (g3 > bestg || (g3 == bestg && c3 < I)) { bestg = g3; I = c3; }
    }

    float H = logf(S) - U / S;                        // per-row entropy (nats)

    out[OUT_IDX + row] = (float)I;
    atomicAdd(&ws[WS_HIST + I], 1.0f);

    const float4* q4 = (const float4*)(emb + (size_t)I * D_DIM);
    float4* oq = (float4*)out + (size_t)row * 16;
    float cs = 0.f;
#pragma unroll
    for (int j = 0; j < 16; ++j) {
        float4 q = q4[j], x = X[j];
        float dx = q.x - x.x, dy = q.y - x.y, dz = q.z - x.z, dw = q.w - x.w;
        cs += dx * dx + dy * dy + dz * dz + dw * dw;
        float4 o;
        o.x = x.x + dx; o.y = x.y + dy; o.z = x.z + dz; o.w = x.w + dw;
        oq[j] = o;
    }
#pragma unroll
    for (int off = 32; off; off >>= 1) {
        H  += __shfl_down(H, off);
        cs += __shfl_down(cs, off);
    }
    if ((t & 63) == 0) { redH[t >> 6] = H; redC[t >> 6] = cs; }
    __syncthreads();
    if (t == 0) {
        atomicAdd(&ws[WS_ACC_H], redH[0] + redH[1] + redH[2] + redH[3]);
        atomicAdd(&ws[WS_ACC_C], redC[0] + redC[1] + redC[2] + redC[3]);
    }
}

// 16 blocks x 256 threads; block b owns codes [64b, 64b+64). Partial 64x64
// Gram of masked-normalized rows, atomicAdd into ws[WS_G].
__global__ __launch_bounds__(256) void vq_ortho_part(const float* __restrict__ emb,
                                                     const float* __restrict__ cc,
                                                     float* __restrict__ ws) {
    __shared__ float srows[64][64];
    __shared__ float rn2[64];

    const int t  = threadIdx.x;
    const int k0 = blockIdx.x * 64;
    const int rb = t >> 4;            // 0..15
    const int c4 = (t & 15) << 2;     // float4 col

#pragma unroll
    for (int i = 0; i < 4; ++i) {
        const int r = i * 16 + rb;
        float4 v = *(const float4*)(emb + (size_t)(k0 + r) * D_DIM + c4);
        *(float4*)(&srows[r][c4]) = v;
        float ss = v.x * v.x + v.y * v.y + v.z * v.z + v.w * v.w;
        ss += __shfl_down(ss, 8, 16);
        ss += __shfl_down(ss, 4, 16);
        ss += __shfl_down(ss, 2, 16);
        ss += __shfl_down(ss, 1, 16);
        if ((t & 15) == 0) {
            float nrm = fmaxf(sqrtf(ss), 1e-12f);
            float m = (cc[k0 + r] >= 1.0f) ? 1.0f : 0.0f;
            rn2[r] = m / (nrm * nrm);     // rnorm^2, folded into A side
        }
    }
    __syncthreads();

    const int a  = t >> 2;
    const int b0 = (t & 3) << 4;
    float acc[16];
#pragma unroll
    for (int i = 0; i < 16; ++i) acc[i] = 0.f;

#pragma unroll 4
    for (int k = 0; k < 64; ++k) {
        float na = srows[k][a] * rn2[k];
        const float* rbp = &srows[k][b0];
#pragma unroll
        for (int i = 0; i < 16; ++i) acc[i] = fmaf(na, rbp[i], acc[i]);
    }
#pragma unroll
    for (int i = 0; i < 16; ++i)
        atomicAdd(&ws[WS_G + a * 64 + b0 + i], acc[i]);
}

__global__ __launch_bounds__(256) void vq_finalize(const float* __restrict__ ws,
                                                   float* __restrict__ out) {
    __shared__ float redP[4], redG[4];
    const int t = threadIdx.x;
    float hp = 0.f, gg = 0.f;
    for (int k = t; k < K_CODES; k += 256) {
        float p = ws[WS_HIST + k] * (1.0f / (float)N_ROWS);
        hp += p * logf(p + 1e-10f);
    }
    for (int i = t; i < 4096; i += 256) {
        float g = ws[WS_G + i];
        gg = fmaf(g, g, gg);
    }
#pragma unroll
    for (int off = 32; off; off >>= 1) {
        hp += __shfl_down(hp, off);
        gg += __shfl_down(gg, off);
    }
    if ((t & 63) == 0) { redP[t >> 6] = hp; redG[t >> 6] = gg; }
    __syncthreads();
    if (t == 0) {
        float hsum = redP[0] + redP[1] + redP[2] + redP[3];
        float gsum = redG[0] + redG[1] + redG[2] + redG[3];
        float nu = ws[WS_NUSED];
        out[OUT_PERP]   = expf(-hsum);
        out[OUT_ENT]    = ws[WS_ACC_H] * (1.0f / (float)N_ROWS) * 0.1f; // /log2(1024)
        out[OUT_COMMIT] = ws[WS_ACC_C] * (1.0f / ((float)N_ROWS * (float)D_DIM));
        out[OUT_ORTHO]  = gsum / (nu * nu) - 1.0f / nu;
        out[OUT_COV]    = nu * (1.0f / (float)K_CODES);
    }
}

extern "C" void kernel_launch(void* const* d_in, const int* in_sizes, int n_in,
                              void* d_out, int out_size, void* d_ws, size_t ws_size,
                              hipStream_t stream) {
    const float* inp = (const float*)d_in[0];   // [16,2048,64]
    const float* emb = (const float*)d_in[1];   // [1024,64]
    const float* cc  = (const float*)d_in[2];   // [1024]
    float* out = (float*)d_out;
    float* ws  = (float*)d_ws;

    hipMemsetAsync(d_ws, 0, MEMSET_BYTES, stream);
    vq_prep<<<16, 256, 0, stream>>>(emb, cc, ws);
    vq_main<<<(N_ROWS / 64) * 2, 256, 0, stream>>>(inp, ws);
    vq_combine<<<N_ROWS / 256, 256, 0, stream>>>(inp, emb, ws, out);
    vq_ortho_part<<<16, 256, 0, stream>>>(emb, cc, ws);
    vq_finalize<<<1, 256, 0, stream>>>(ws, out);
}